// Round 6
// baseline (273.133 us; speedup 1.0000x reference)
//
#include <hip/hip_runtime.h>

#define N_ 4
#define L_ 1024
#define H_ 8
#define D_ 64

typedef _Float16 f16x8 __attribute__((ext_vector_type(8)));
typedef float f32x4 __attribute__((ext_vector_type(4)));

#define MFMA(A, B, C) __builtin_amdgcn_mfma_f32_16x16x32_f16(A, B, C, 0, 0, 0)

__device__ __forceinline__ ushort f2h(float x) {
    union { _Float16 h; ushort u; } c;
    c.h = (_Float16)x;
    return c.u;
}
__device__ __forceinline__ f16x8 ld8(const ushort* p) {
    return *(const f16x8*)p;
}
__device__ __forceinline__ f16x8 negf(f16x8 a) {
    uint4 u = __builtin_bit_cast(uint4, a);
    u.x ^= 0x80008000u; u.y ^= 0x80008000u; u.z ^= 0x80008000u; u.w ^= 0x80008000u;
    return __builtin_bit_cast(f16x8, u);
}
// load 8 consecutive f32, scale by (1/8)*log2(e), convert to f16x8
__device__ __forceinline__ f16x8 cvt8(const float* p) {
    const float SCQ = 0.18033688011112f;
    float4 a = *(const float4*)p;
    float4 b = *(const float4*)(p + 4);
    union { f16x8 v; _Float16 e[8]; } u;
    u.e[0] = (_Float16)(a.x * SCQ); u.e[1] = (_Float16)(a.y * SCQ);
    u.e[2] = (_Float16)(a.z * SCQ); u.e[3] = (_Float16)(a.w * SCQ);
    u.e[4] = (_Float16)(b.x * SCQ); u.e[5] = (_Float16)(b.y * SCQ);
    u.e[6] = (_Float16)(b.z * SCQ); u.e[7] = (_Float16)(b.w * SCQ);
    return u.v;
}

// ---- convert K: fp32 [n][l][h][d] -> f16 [aid][n][h][l][d], aid in {kr,ki}
__global__ void cvt_k(const float* __restrict__ k_r, const float* __restrict__ k_i,
                      ushort* __restrict__ dst) {
    int gid = blockIdx.x * 256 + threadIdx.x;   // 0..1048575 (x4 elems each)
    int aid = gid >> 19;
    int idx = (gid & 0x7FFFF) << 2;             // flat [n][h][l][d]
    int d  = idx & 63;
    int l  = (idx >> 6) & 1023;
    int hh = (idx >> 16) & 7;
    int n  = idx >> 19;
    const float* src = aid ? k_i : k_r;
    const float4 v = *(const float4*)(src + (((long)n * 1024 + l) * 8 + hh) * 64 + d);
    ushort4 o = make_ushort4(f2h(v.x), f2h(v.y), f2h(v.z), f2h(v.w));
    *(ushort4*)(dst + ((long)aid << 21) + idx) = o;
}

// ---- convert V: fp32 [n][s][h][d] -> f16 transposed [aid][n][h][d][s]
__global__ void cvt_v(const float* __restrict__ vr, const float* __restrict__ vi,
                      ushort* __restrict__ dst) {
    __shared__ ushort t[64][72];
    int bid = blockIdx.x;
    int aid = bid >> 9;
    int b   = bid & 511;
    int s0  = (b & 15) << 6;
    int hh  = (b >> 4) & 7;
    int n   = b >> 7;
    const float* src = aid ? vi : vr;
    int tid = threadIdx.x;
    int r  = tid >> 4;
    int cq = (tid & 15) << 2;
#pragma unroll
    for (int it = 0; it < 4; ++it) {
        int s = s0 + it * 16 + r;
        const float4 v = *(const float4*)(src + (((long)n * 1024 + s) * 8 + hh) * 64 + cq);
        t[it * 16 + r][cq + 0] = f2h(v.x);
        t[it * 16 + r][cq + 1] = f2h(v.y);
        t[it * 16 + r][cq + 2] = f2h(v.z);
        t[it * 16 + r][cq + 3] = f2h(v.w);
    }
    __syncthreads();
#pragma unroll
    for (int it = 0; it < 4; ++it) {
        int dd = it * 16 + r;
        ushort4 o;
        o.x = t[cq + 0][dd]; o.y = t[cq + 1][dd]; o.z = t[cq + 2][dd]; o.w = t[cq + 3][dd];
        *(ushort4*)(dst + ((long)aid << 21) + (((long)n * 8 + hh) * 64 + dd) * 1024 + s0 + cq) = o;
    }
}

// scores for sub-block sb of chunk c -> a0 (real exp2-arg), a1 (imag exp2-arg)
// Q fragments pre-scaled by (1/8)*log2(e).
#define SCORES(c, sbi, a0, a1)                                              \
    do {                                                                    \
        const long soff = (long)((c) * 64 + (sbi) * 16 + col) * 64 + g * 8; \
        f16x8 kr0v = ld8(Kr + soff), kr1v = ld8(Kr + soff + 32);            \
        f16x8 ki0v = ld8(Ki + soff), ki1v = ld8(Ki + soff + 32);            \
        a0 = (f32x4){0.f, 0.f, 0.f, 0.f};                                   \
        a0 = MFMA(qr0, kr0v, a0); a0 = MFMA(qr1, kr1v, a0);                 \
        a0 = MFMA(qi0, negf(ki0v), a0); a0 = MFMA(qi1, negf(ki1v), a0);     \
        a1 = (f32x4){0.f, 0.f, 0.f, 0.f};                                   \
        a1 = MFMA(qr0, ki0v, a1); a1 = MFMA(qr1, ki1v, a1);                 \
        a1 = MFMA(qi0, kr0v, a1); a1 = MFMA(qi1, kr1v, a1);                 \
    } while (0)

#define BFLY(x)                                                             \
    x += __shfl_xor(x, 1); x += __shfl_xor(x, 2);                           \
    x += __shfl_xor(x, 4); x += __shfl_xor(x, 8);

// ws element layout (ushort): Kr @0, Ki @1<<21, Vr @2<<21, Vi @3<<21 (16 MB)
// rdbuf (float): byte offset 16 MB, 2*32768 floats.

// ---- single-pass attention for u + rd ----
// grid 512 (XCD-swizzled -> (nh, l-tile64)), block 256 = 4 waves (same nh),
// wave owns 16 rows. No-max softmax; SEPARATE accumulators per (P-part,
// V-part) pair because real/imag denominators differ:
//   u_real = uRR*rdR - uII*rdI ; u_imag = uRI*rdR + uIR*rdI.
__launch_bounds__(256, 2)
__global__ void attn_u(const float* __restrict__ qr_g, const float* __restrict__ qi_g,
                       const ushort* __restrict__ ws, float* __restrict__ rdbuf,
                       float* __restrict__ out) {
    __shared__ ushort wtile[4][2][1024];   // [wave][part][16*64] swizzled

    const int tid  = threadIdx.x;
    const int lane = tid & 63;
    const int wq   = tid >> 6;
    const int col  = lane & 15;
    const int g    = lane >> 4;

    // XCD swizzle: XCD x serves nh in [4x, 4x+4) -> 2MB K+V slice per L2
    const int id = blockIdx.x;
    const int x  = id & 7;
    const int q  = id >> 3;
    const int nh = x * 4 + (q >> 4);
    const int n  = nh >> 3;
    const int h  = nh & 7;
    const int l0 = (q & 15) * 64 + wq * 16;

    const ushort* Kr = ws + ((long)nh << 16);                 // [1024][64]
    const ushort* Ki = ws + (1l << 21) + ((long)nh << 16);
    const ushort* Vr = ws + (2l << 21) + ((long)nh << 16);    // [64][1024]
    const ushort* Vi = ws + (3l << 21) + ((long)nh << 16);

    // Q fragments: convert from fp32 in-kernel (row = col, k = g*8+e, +32)
    const long qg = (((long)n * 1024 + l0 + col) * 8 + h) * 64 + g * 8;
    const f16x8 qr0 = cvt8(qr_g + qg), qr1 = cvt8(qr_g + qg + 32);
    const f16x8 qi0 = cvt8(qi_g + qg), qi1 = cvt8(qi_g + qg + 32);

    ushort* wbr = &wtile[wq][0][0];
    ushort* wbi = &wtile[wq][1][0];

    float dRs[4] = {0.f, 0.f, 0.f, 0.f};
    float dIs[4] = {0.f, 0.f, 0.f, 0.f};
    f32x4 uRR[4], uII[4], uRI[4], uIR[4];
#pragma unroll
    for (int db = 0; db < 4; ++db) {
        uRR[db] = (f32x4){0.f, 0.f, 0.f, 0.f};
        uII[db] = (f32x4){0.f, 0.f, 0.f, 0.f};
        uRI[db] = (f32x4){0.f, 0.f, 0.f, 0.f};
        uIR[db] = (f32x4){0.f, 0.f, 0.f, 0.f};
    }

    for (int c = 0; c < 16; ++c) {
#pragma unroll
        for (int sb = 0; sb < 4; ++sb) {
            f32x4 a0, a1;
            SCORES(c, sb, a0, a1);
#pragma unroll
            for (int r = 0; r < 4; ++r) {
                const float wf = exp2f(a0[r]);
                const float vf = exp2f(a1[r]);
                dRs[r] += wf;
                dIs[r] += vf;
                const int row = 4 * g + r;
                const int us = (sb * 16 + col) ^ ((row & 7) << 3);
                wbr[row * 64 + us] = f2h(wf);
                wbi[row * 64 + us] = f2h(vf);
            }
        }
        // A-frag reads (wave-private LDS; in-wave ds order + lgkmcnt suffice)
        const int xr  = ((g ^ (col & 7)) << 3);
        const int xr2 = (((g + 4) ^ (col & 7)) << 3);
        f16x8 wr0 = ld8(&wbr[col * 64 + xr]);
        f16x8 wr1 = ld8(&wbr[col * 64 + xr2]);
        f16x8 wi0 = ld8(&wbi[col * 64 + xr]);
        f16x8 wi1 = ld8(&wbi[col * 64 + xr2]);
#pragma unroll
        for (int db = 0; db < 4; ++db) {
            const ushort* vrb = Vr + (long)(db * 16 + col) * 1024 + c * 64 + g * 8;
            f16x8 vr0 = ld8(vrb), vr1 = ld8(vrb + 32);
            const ushort* vib = Vi + (long)(db * 16 + col) * 1024 + c * 64 + g * 8;
            f16x8 vi0 = ld8(vib), vi1 = ld8(vib + 32);
            uRR[db] = MFMA(wr0, vr0, uRR[db]); uRR[db] = MFMA(wr1, vr1, uRR[db]);
            uII[db] = MFMA(wi0, vi0, uII[db]); uII[db] = MFMA(wi1, vi1, uII[db]);
            uRI[db] = MFMA(wr0, vi0, uRI[db]); uRI[db] = MFMA(wr1, vi1, uRI[db]);
            uIR[db] = MFMA(wi0, vr0, uIR[db]); uIR[db] = MFMA(wi1, vr1, uIR[db]);
        }
    }

    BFLY(dRs[0]) BFLY(dRs[1]) BFLY(dRs[2]) BFLY(dRs[3])
    BFLY(dIs[0]) BFLY(dIs[1]) BFLY(dIs[2]) BFLY(dIs[3])

    float rdR[4], rdI[4];
#pragma unroll
    for (int r = 0; r < 4; ++r) { rdR[r] = 1.f / dRs[r]; rdI[r] = 1.f / dIs[r]; }

    if (col == 0) {
#pragma unroll
        for (int r = 0; r < 4; ++r) {
            rdbuf[nh * 1024 + l0 + 4 * g + r] = rdR[r];
            rdbuf[32768 + nh * 1024 + l0 + 4 * g + r] = rdI[r];
        }
    }

    const long OFF_UI = 2097152;
#pragma unroll
    for (int db = 0; db < 4; ++db) {
#pragma unroll
        for (int r = 0; r < 4; ++r) {
            const int l = l0 + 4 * g + r;
            const int d = db * 16 + col;
            const long base = (((long)n * L_ + l) * H_ + h) * D_ + d;
            out[base] = uRR[db][r] * rdR[r] - uII[db][r] * rdI[r];
            out[OFF_UI + base] = uRI[db][r] * rdR[r] + uIR[db][r] * rdI[r];
        }
    }
}

// ---- a = 0.125 * sum_h exp2(arg_h) * rd_h ---- recompute QK^T per head
// grid 256 (XCD-swizzled -> (n, l-tile16)), block 256 = 4 waves = 4 s-quarters.
// Per-head normalization happens BEFORE the h-sum, so this is exact.
__launch_bounds__(256, 2)
__global__ void kern_a(const float* __restrict__ qr_g, const float* __restrict__ qi_g,
                       const ushort* __restrict__ ws, const float* __restrict__ rdbuf,
                       float* __restrict__ out) {
    __shared__ float lrd[8][2][16];   // [h][part][row]

    const int tid  = threadIdx.x;
    const int lane = tid & 63;
    const int wq   = tid >> 6;        // s-quarter
    const int col  = lane & 15;
    const int g    = lane >> 4;

    // XCD swizzle: XCD x serves n = x>>1 (2 XCDs per n, K(n)=2MB per L2)
    const int id = blockIdx.x;
    const int x  = id & 7;
    const int q  = id >> 3;           // 0..31
    const int n  = x >> 1;
    const int l0 = ((x & 1) * 32 + q) * 16;

    // preload rd for all heads/rows of this tile: tid -> (h, part, row)
    lrd[tid >> 5][(tid >> 4) & 1][tid & 15] =
        rdbuf[((tid >> 4) & 1) * 32768 + (n * 8 + (tid >> 5)) * 1024 + l0 + (tid & 15)];
    __syncthreads();

    f32x4 aR[16], aI[16];
#pragma unroll
    for (int i = 0; i < 16; ++i) {
        aR[i] = (f32x4){0.f, 0.f, 0.f, 0.f};
        aI[i] = (f32x4){0.f, 0.f, 0.f, 0.f};
    }

    for (int h = 0; h < 8; ++h) {
        const int nh = n * 8 + h;
        const ushort* Kr = ws + ((long)nh << 16);
        const ushort* Ki = ws + (1l << 21) + ((long)nh << 16);
        const long qg = (((long)n * 1024 + l0 + col) * 8 + h) * 64 + g * 8;
        const f16x8 qr0 = cvt8(qr_g + qg), qr1 = cvt8(qr_g + qg + 32);
        const f16x8 qi0 = cvt8(qi_g + qg), qi1 = cvt8(qi_g + qg + 32);
        float rdR[4], rdI[4];
#pragma unroll
        for (int r = 0; r < 4; ++r) {
            rdR[r] = lrd[h][0][4 * g + r];
            rdI[r] = lrd[h][1][4 * g + r];
        }
#pragma unroll
        for (int c4 = 0; c4 < 4; ++c4) {
            const int c = wq * 4 + c4;
#pragma unroll
            for (int sb = 0; sb < 4; ++sb) {
                f32x4 a0, a1;
                SCORES(c, sb, a0, a1);
                const int sbq = c4 * 4 + sb;
#pragma unroll
                for (int r = 0; r < 4; ++r) {
                    aR[sbq][r] += exp2f(a0[r]) * rdR[r];
                    aI[sbq][r] += exp2f(a1[r]) * rdI[r];
                }
            }
        }
    }

    const long OFF_AR = 4194304;
    const long OFF_AI = 8388608;
#pragma unroll
    for (int sbq = 0; sbq < 16; ++sbq) {
#pragma unroll
        for (int r = 0; r < 4; ++r) {
            const int l = l0 + 4 * g + r;
            const int s = wq * 256 + sbq * 16 + col;
            const long ab = ((long)n * 1024 + l) * 1024 + s;
            out[OFF_AR + ab] = aR[sbq][r] * 0.125f;
            out[OFF_AI + ab] = aI[sbq][r] * 0.125f;
        }
    }
}

extern "C" void kernel_launch(void* const* d_in, const int* in_sizes, int n_in,
                              void* d_out, int out_size, void* d_ws, size_t ws_size,
                              hipStream_t stream) {
    const float* qr = (const float*)d_in[0];
    const float* qi = (const float*)d_in[1];
    const float* kr = (const float*)d_in[2];
    const float* ki = (const float*)d_in[3];
    const float* vr = (const float*)d_in[4];
    const float* vi = (const float*)d_in[5];
    ushort* ws = (ushort*)d_ws;                              // 16 MB f16 K/V
    float* rdbuf = (float*)((char*)d_ws + (16ull << 20));    // 256 KB @ 16 MB
    float* out = (float*)d_out;

    hipLaunchKernelGGL(cvt_k, dim3(4096), dim3(256), 0, stream, kr, ki, ws);
    hipLaunchKernelGGL(cvt_v, dim3(1024), dim3(256), 0, stream, vr, vi, ws + (2l << 21));
    hipLaunchKernelGGL(attn_u, dim3(512), dim3(256), 0, stream, qr, qi, ws, rdbuf, out);
    hipLaunchKernelGGL(kern_a, dim3(256), dim3(256), 0, stream, qr, qi, ws, rdbuf, out);
}

// Round 7
// 227.298 us; speedup vs baseline: 1.2017x; 1.2017x over previous
//
#include <hip/hip_runtime.h>

#define N_ 4
#define L_ 1024
#define H_ 8
#define D_ 64

typedef _Float16 f16x8 __attribute__((ext_vector_type(8)));
typedef float f32x4 __attribute__((ext_vector_type(4)));

#define MFMA(A, B, C) __builtin_amdgcn_mfma_f32_16x16x32_f16(A, B, C, 0, 0, 0)

__device__ __forceinline__ ushort f2h(float x) {
    union { _Float16 h; ushort u; } c;
    c.h = (_Float16)x;
    return c.u;
}
__device__ __forceinline__ f16x8 ld8(const ushort* p) {
    return *(const f16x8*)p;
}
__device__ __forceinline__ f16x8 negf(f16x8 a) {
    uint4 u = __builtin_bit_cast(uint4, a);
    u.x ^= 0x80008000u; u.y ^= 0x80008000u; u.z ^= 0x80008000u; u.w ^= 0x80008000u;
    return __builtin_bit_cast(f16x8, u);
}
// load 8 consecutive f32, scale by (1/8)*log2(e), convert to f16x8
__device__ __forceinline__ f16x8 cvt8(const float* p) {
    const float SCQ = 0.18033688011112f;
    float4 a = *(const float4*)p;
    float4 b = *(const float4*)(p + 4);
    union { f16x8 v; _Float16 e[8]; } u;
    u.e[0] = (_Float16)(a.x * SCQ); u.e[1] = (_Float16)(a.y * SCQ);
    u.e[2] = (_Float16)(a.z * SCQ); u.e[3] = (_Float16)(a.w * SCQ);
    u.e[4] = (_Float16)(b.x * SCQ); u.e[5] = (_Float16)(b.y * SCQ);
    u.e[6] = (_Float16)(b.z * SCQ); u.e[7] = (_Float16)(b.w * SCQ);
    return u.v;
}

// ---- convert K: fp32 [n][l][h][d] -> f16 [aid][n][h][l][d], aid in {kr,ki}
__global__ void cvt_k(const float* __restrict__ k_r, const float* __restrict__ k_i,
                      ushort* __restrict__ dst) {
    int gid = blockIdx.x * 256 + threadIdx.x;   // 0..1048575 (x4 elems each)
    int aid = gid >> 19;
    int idx = (gid & 0x7FFFF) << 2;             // flat [n][h][l][d]
    int d  = idx & 63;
    int l  = (idx >> 6) & 1023;
    int hh = (idx >> 16) & 7;
    int n  = idx >> 19;
    const float* src = aid ? k_i : k_r;
    const float4 v = *(const float4*)(src + (((long)n * 1024 + l) * 8 + hh) * 64 + d);
    ushort4 o = make_ushort4(f2h(v.x), f2h(v.y), f2h(v.z), f2h(v.w));
    *(ushort4*)(dst + ((long)aid << 21) + idx) = o;
}

// ---- convert V: fp32 [n][s][h][d] -> f16 transposed [aid][n][h][d][s]
__global__ void cvt_v(const float* __restrict__ vr, const float* __restrict__ vi,
                      ushort* __restrict__ dst) {
    __shared__ ushort t[64][72];
    int bid = blockIdx.x;
    int aid = bid >> 9;
    int b   = bid & 511;
    int s0  = (b & 15) << 6;
    int hh  = (b >> 4) & 7;
    int n   = b >> 7;
    const float* src = aid ? vi : vr;
    int tid = threadIdx.x;
    int r  = tid >> 4;
    int cq = (tid & 15) << 2;
#pragma unroll
    for (int it = 0; it < 4; ++it) {
        int s = s0 + it * 16 + r;
        const float4 v = *(const float4*)(src + (((long)n * 1024 + s) * 8 + hh) * 64 + cq);
        t[it * 16 + r][cq + 0] = f2h(v.x);
        t[it * 16 + r][cq + 1] = f2h(v.y);
        t[it * 16 + r][cq + 2] = f2h(v.z);
        t[it * 16 + r][cq + 3] = f2h(v.w);
    }
    __syncthreads();
#pragma unroll
    for (int it = 0; it < 4; ++it) {
        int dd = it * 16 + r;
        ushort4 o;
        o.x = t[cq + 0][dd]; o.y = t[cq + 1][dd]; o.z = t[cq + 2][dd]; o.w = t[cq + 3][dd];
        *(ushort4*)(dst + ((long)aid << 21) + (((long)n * 8 + hh) * 64 + dd) * 1024 + s0 + cq) = o;
    }
}

// scores for sub-block sb of chunk c -> a0 (real exp2-arg), a1 (imag exp2-arg)
// Q fragments pre-scaled by (1/8)*log2(e).
#define SCORES(c, sbi, a0, a1)                                              \
    do {                                                                    \
        const long soff = (long)((c) * 64 + (sbi) * 16 + col) * 64 + g * 8; \
        f16x8 kr0v = ld8(Kr + soff), kr1v = ld8(Kr + soff + 32);            \
        f16x8 ki0v = ld8(Ki + soff), ki1v = ld8(Ki + soff + 32);            \
        a0 = (f32x4){0.f, 0.f, 0.f, 0.f};                                   \
        a0 = MFMA(qr0, kr0v, a0); a0 = MFMA(qr1, kr1v, a0);                 \
        a0 = MFMA(qi0, negf(ki0v), a0); a0 = MFMA(qi1, negf(ki1v), a0);     \
        a1 = (f32x4){0.f, 0.f, 0.f, 0.f};                                   \
        a1 = MFMA(qr0, ki0v, a1); a1 = MFMA(qr1, ki1v, a1);                 \
        a1 = MFMA(qi0, kr0v, a1); a1 = MFMA(qi1, kr1v, a1);                 \
    } while (0)

#define BFLY(x)                                                             \
    x += __shfl_xor(x, 1); x += __shfl_xor(x, 2);                           \
    x += __shfl_xor(x, 4); x += __shfl_xor(x, 8);

// ws element layout (ushort): Kr @0, Ki @1<<21, Vr @2<<21, Vi @3<<21 (16 MB)
// rdbuf (float): byte offset 16 MB, 2*32768 floats.

// ---- single-pass attention for u + rd ----
// grid 512 (XCD-swizzled -> (nh, l-tile64)), block 256 = 4 waves (same nh),
// wave owns 16 rows. No-max softmax; SEPARATE accumulators per (P-part,
// V-part) pair because real/imag denominators differ:
//   u_real = uRR*rdR - uII*rdI ; u_imag = uRI*rdR + uIR*rdI.
__launch_bounds__(256, 2)
__global__ void attn_u(const float* __restrict__ qr_g, const float* __restrict__ qi_g,
                       const ushort* __restrict__ ws, float* __restrict__ rdbuf,
                       float* __restrict__ out) {
    __shared__ ushort wtile[4][2][1024];   // [wave][part][16*64] swizzled

    const int tid  = threadIdx.x;
    const int lane = tid & 63;
    const int wq   = tid >> 6;
    const int col  = lane & 15;
    const int g    = lane >> 4;

    // XCD swizzle: XCD x serves nh in [4x, 4x+4) -> 2MB K+V slice per L2
    const int id = blockIdx.x;
    const int x  = id & 7;
    const int q  = id >> 3;
    const int nh = x * 4 + (q >> 4);
    const int n  = nh >> 3;
    const int h  = nh & 7;
    const int l0 = (q & 15) * 64 + wq * 16;

    const ushort* Kr = ws + ((long)nh << 16);                 // [1024][64]
    const ushort* Ki = ws + (1l << 21) + ((long)nh << 16);
    const ushort* Vr = ws + (2l << 21) + ((long)nh << 16);    // [64][1024]
    const ushort* Vi = ws + (3l << 21) + ((long)nh << 16);

    // Q fragments: convert from fp32 in-kernel (row = col, k = g*8+e, +32)
    const long qg = (((long)n * 1024 + l0 + col) * 8 + h) * 64 + g * 8;
    const f16x8 qr0 = cvt8(qr_g + qg), qr1 = cvt8(qr_g + qg + 32);
    const f16x8 qi0 = cvt8(qi_g + qg), qi1 = cvt8(qi_g + qg + 32);

    ushort* wbr = &wtile[wq][0][0];
    ushort* wbi = &wtile[wq][1][0];

    float dRs[4] = {0.f, 0.f, 0.f, 0.f};
    float dIs[4] = {0.f, 0.f, 0.f, 0.f};
    f32x4 uRR[4], uII[4], uRI[4], uIR[4];
#pragma unroll
    for (int db = 0; db < 4; ++db) {
        uRR[db] = (f32x4){0.f, 0.f, 0.f, 0.f};
        uII[db] = (f32x4){0.f, 0.f, 0.f, 0.f};
        uRI[db] = (f32x4){0.f, 0.f, 0.f, 0.f};
        uIR[db] = (f32x4){0.f, 0.f, 0.f, 0.f};
    }

    for (int c = 0; c < 16; ++c) {
#pragma unroll
        for (int sb = 0; sb < 4; ++sb) {
            f32x4 a0, a1;
            SCORES(c, sb, a0, a1);
#pragma unroll
            for (int r = 0; r < 4; ++r) {
                const float wf = exp2f(a0[r]);
                const float vf = exp2f(a1[r]);
                dRs[r] += wf;
                dIs[r] += vf;
                const int row = 4 * g + r;
                const int us = (sb * 16 + col) ^ ((row & 7) << 3);
                wbr[row * 64 + us] = f2h(wf);
                wbi[row * 64 + us] = f2h(vf);
            }
        }
        // A-frag reads (wave-private LDS; in-wave ds order + lgkmcnt suffice)
        const int xr  = ((g ^ (col & 7)) << 3);
        const int xr2 = (((g + 4) ^ (col & 7)) << 3);
        f16x8 wr0 = ld8(&wbr[col * 64 + xr]);
        f16x8 wr1 = ld8(&wbr[col * 64 + xr2]);
        f16x8 wi0 = ld8(&wbi[col * 64 + xr]);
        f16x8 wi1 = ld8(&wbi[col * 64 + xr2]);
#pragma unroll
        for (int db = 0; db < 4; ++db) {
            const ushort* vrb = Vr + (long)(db * 16 + col) * 1024 + c * 64 + g * 8;
            f16x8 vr0 = ld8(vrb), vr1 = ld8(vrb + 32);
            const ushort* vib = Vi + (long)(db * 16 + col) * 1024 + c * 64 + g * 8;
            f16x8 vi0 = ld8(vib), vi1 = ld8(vib + 32);
            uRR[db] = MFMA(wr0, vr0, uRR[db]); uRR[db] = MFMA(wr1, vr1, uRR[db]);
            uII[db] = MFMA(wi0, vi0, uII[db]); uII[db] = MFMA(wi1, vi1, uII[db]);
            uRI[db] = MFMA(wr0, vi0, uRI[db]); uRI[db] = MFMA(wr1, vi1, uRI[db]);
            uIR[db] = MFMA(wi0, vr0, uIR[db]); uIR[db] = MFMA(wi1, vr1, uIR[db]);
        }
    }

    BFLY(dRs[0]) BFLY(dRs[1]) BFLY(dRs[2]) BFLY(dRs[3])
    BFLY(dIs[0]) BFLY(dIs[1]) BFLY(dIs[2]) BFLY(dIs[3])

    float rdR[4], rdI[4];
#pragma unroll
    for (int r = 0; r < 4; ++r) { rdR[r] = 1.f / dRs[r]; rdI[r] = 1.f / dIs[r]; }

    if (col == 0) {
#pragma unroll
        for (int r = 0; r < 4; ++r) {
            rdbuf[nh * 1024 + l0 + 4 * g + r] = rdR[r];
            rdbuf[32768 + nh * 1024 + l0 + 4 * g + r] = rdI[r];
        }
    }

    const long OFF_UI = 2097152;
#pragma unroll
    for (int db = 0; db < 4; ++db) {
#pragma unroll
        for (int r = 0; r < 4; ++r) {
            const int l = l0 + 4 * g + r;
            const int d = db * 16 + col;
            const long base = (((long)n * L_ + l) * H_ + h) * D_ + d;
            out[base] = uRR[db][r] * rdR[r] - uII[db][r] * rdI[r];
            out[OFF_UI + base] = uRI[db][r] * rdR[r] + uIR[db][r] * rdI[r];
        }
    }
}

// ---- a = 0.125 * sum_h exp2(arg_h) * rd_h ---- recompute QK^T per head
// grid 1024 (XCD-swizzled -> (n, l-tile16, s-quarter)), block 256 = 4 waves;
// wave owns ONE 64-col s-chunk -> acc = 32 VGPR, 16 waves/CU.
__launch_bounds__(256, 4)
__global__ void kern_a(const float* __restrict__ qr_g, const float* __restrict__ qi_g,
                       const ushort* __restrict__ ws, const float* __restrict__ rdbuf,
                       float* __restrict__ out) {
    __shared__ float lrd[8][2][16];   // [h][part][row]

    const int tid  = threadIdx.x;
    const int lane = tid & 63;
    const int wq   = tid >> 6;
    const int col  = lane & 15;
    const int g    = lane >> 4;

    // XCD swizzle: id&7 = XCD; XCD x serves n = x>>1 (K(n) = 2MB per L2)
    const int id  = blockIdx.x;
    const int nid = (id & 7) * 128 + (id >> 3);   // bijective on [0,1024)
    const int n   = nid >> 8;
    const int rem = nid & 255;
    const int l0  = (rem >> 2) << 4;
    const int sq  = rem & 3;
    const int c   = sq * 4 + wq;      // this wave's 64-col chunk

    // preload rd for all heads/rows of this tile: tid -> (h, part, row)
    lrd[tid >> 5][(tid >> 4) & 1][tid & 15] =
        rdbuf[((tid >> 4) & 1) * 32768 + (n * 8 + (tid >> 5)) * 1024 + l0 + (tid & 15)];
    __syncthreads();

    f32x4 aR[4], aI[4];
#pragma unroll
    for (int i = 0; i < 4; ++i) {
        aR[i] = (f32x4){0.f, 0.f, 0.f, 0.f};
        aI[i] = (f32x4){0.f, 0.f, 0.f, 0.f};
    }

    for (int h = 0; h < 8; ++h) {
        const int nh = n * 8 + h;
        const ushort* Kr = ws + ((long)nh << 16);
        const ushort* Ki = ws + (1l << 21) + ((long)nh << 16);
        const long qg = (((long)n * 1024 + l0 + col) * 8 + h) * 64 + g * 8;
        const f16x8 qr0 = cvt8(qr_g + qg), qr1 = cvt8(qr_g + qg + 32);
        const f16x8 qi0 = cvt8(qi_g + qg), qi1 = cvt8(qi_g + qg + 32);
        float rdR[4], rdI[4];
#pragma unroll
        for (int r = 0; r < 4; ++r) {
            rdR[r] = lrd[h][0][4 * g + r];
            rdI[r] = lrd[h][1][4 * g + r];
        }
#pragma unroll
        for (int sb = 0; sb < 4; ++sb) {
            f32x4 a0, a1;
            SCORES(c, sb, a0, a1);
#pragma unroll
            for (int r = 0; r < 4; ++r) {
                aR[sb][r] += exp2f(a0[r]) * rdR[r];
                aI[sb][r] += exp2f(a1[r]) * rdI[r];
            }
        }
    }

    const long OFF_AR = 4194304;
    const long OFF_AI = 8388608;
#pragma unroll
    for (int sb = 0; sb < 4; ++sb) {
#pragma unroll
        for (int r = 0; r < 4; ++r) {
            const int l = l0 + 4 * g + r;
            const int s = c * 64 + sb * 16 + col;
            const long ab = ((long)n * 1024 + l) * 1024 + s;
            out[OFF_AR + ab] = aR[sb][r] * 0.125f;
            out[OFF_AI + ab] = aI[sb][r] * 0.125f;
        }
    }
}

extern "C" void kernel_launch(void* const* d_in, const int* in_sizes, int n_in,
                              void* d_out, int out_size, void* d_ws, size_t ws_size,
                              hipStream_t stream) {
    const float* qr = (const float*)d_in[0];
    const float* qi = (const float*)d_in[1];
    const float* kr = (const float*)d_in[2];
    const float* ki = (const float*)d_in[3];
    const float* vr = (const float*)d_in[4];
    const float* vi = (const float*)d_in[5];
    ushort* ws = (ushort*)d_ws;                              // 16 MB f16 K/V
    float* rdbuf = (float*)((char*)d_ws + (16ull << 20));    // 256 KB @ 16 MB
    float* out = (float*)d_out;

    hipLaunchKernelGGL(cvt_k, dim3(4096), dim3(256), 0, stream, kr, ki, ws);
    hipLaunchKernelGGL(cvt_v, dim3(1024), dim3(256), 0, stream, vr, vi, ws + (2l << 21));
    hipLaunchKernelGGL(attn_u, dim3(512), dim3(256), 0, stream, qr, qi, ws, rdbuf, out);
    hipLaunchKernelGGL(kern_a, dim3(1024), dim3(256), 0, stream, qr, qi, ws, rdbuf, out);
}